// Round 8
// baseline (497677.246 us; speedup 1.0000x reference)
//
#include <hip/hip_runtime.h>
#include <stdint.h>

// Problem constants (B,S,I,H,O) = (64, 2048, 256, 512, 256), all fp32.
#define Bn 64
#define Sn 2048
#define In 256
#define Hn 512
#define On 256
#define TT 16      // timesteps per xw-precompute tile
#define CH 32      // fallback-path chunk rows

// v9 scan tiering (256 threads, 2 cols/thread, float2 granularity):
//   rows 0..RK-1     -> VGPR   (float2 wr[RK] = 2*RK regs)
//   rows RK..RK+LK-1 -> LDS    (LK*2KB)
//   rows RK+LK..511  -> streamed from L2
#define RK 128
#define LK 64
#define SK (Hn - RK - LK)   // 320 streamed rows
#define SC 16               // rows per stream chunk
#define NCH (SK / SC)       // 20 chunks; NCH % 4 == 0 -> steady 4-buffer rotation

// ---------------------------------------------------------------------------
// BIT-EXACT constraint (proven, absmax 0.0): per output element
//   xacc = fma-chain_{i=0..255 asc}(x[i], Wxh[i][j]);  xw = xacc + bias_h[j]
//   hacc = fma-chain_{k=0..511 asc}(h[k], Whh[k][j]);  u  = xw + hacc
//   h' = xla_tanh(u);   y = fma-chain_k(h[k],Why[k][o]) + bias_y[o]
//
// DESIGN v9 — evidence ledger:
//  v0 (33.7ms): cross-block rendezvous -> 16.4us/step protocol latency.
//     PROVED: 256thr + __launch_bounds__(256,1) holds ~420 floats/thread
//     in the unified VGPR/AGPR file with NO spill.
//  v2-v5 (~120ms): agent-scope polling saturates coherent fabric. Dead end.
//  v6 (328ms): 512-reg cliff -> spill catastrophe (WRITE 49.7GB).
//  v7 (30.0ms): zero inter-block comm; Whh 1MB/step streamed from XCD L2.
//     Step 14.3us = 1MB / ~70GB/s per-CU delivery. WRITE 128B. DELIVERY-BOUND.
//  v8 (39.8ms): 3-tier @512thr: compiler capped VGPR=128, spilled wr[128]
//     (WRITE 33.8MB); scratch re-reads restored ~1MB/step delivery. Lesson:
//     the tier plan only works in the v0-proven register configuration.
// v9 = v8's tiering in v0's register regime:
//   * 256 threads, 1 block/batch (64 blocks), 2 cols/thread, bounds(256,1).
//   * regs: wr[128] float2 (256) + 4 stream bufs (128) + misc ~30 = ~414,
//     inside the proven no-spill zone. All statically indexed.
//   * LDS: wl[64][512] = 128KB + hs 4KB = 132KB (v8-launch-proven size).
//   * stream: 640KB/step (0.62x v7), distance-4 wrap prefetch, steady
//     rotation across steps (tail of step t issues chunks 0..3 of t+1).
//   * hacc: SAME single acc per col, k ascending; only W source varies.
// VALIDATION: WRITE_SIZE must stay ~100B. MBs => spill => round void.
// ---------------------------------------------------------------------------

__device__ __forceinline__ float xla_tanh(float x) {
    const float ax = __builtin_fabsf(x);
    float xc = fmaxf(-7.99881172180175781f, fminf(7.99881172180175781f, x));
    const float x2 = xc * xc;
    float p = fmaf(x2, -2.76076847742355e-16f, 2.00018790482477e-13f);
    p = fmaf(x2, p, -8.60467152213735e-11f);
    p = fmaf(x2, p, 5.12229709037114e-08f);
    p = fmaf(x2, p, 1.48572235717979e-05f);
    p = fmaf(x2, p, 6.37261928875436e-04f);
    p = fmaf(x2, p, 4.89352455891786e-03f);
    p = xc * p;
    float q = fmaf(x2, 1.19825839466702e-06f, 1.18534705686654e-04f);
    q = fmaf(x2, q, 2.26843463243900e-03f);
    q = fmaf(x2, q, 4.89352518554385e-03f);
    return ax < 0.0004f ? x : p / q;
}

// ---------------------------------------------------------------------------
// xw[b][t][j] = bias_h[j] + fma-chain_{i asc}(x[b][t][i], Wxh[i][j])
// (proven bit-exact in v7)
// ---------------------------------------------------------------------------
__global__ __launch_bounds__(512) void xw_gemm(const float* __restrict__ x,
                                               const float* __restrict__ Wxh,
                                               const float* __restrict__ bias_h,
                                               float* __restrict__ xw) {
    const int b = blockIdx.x >> 7;               // Sn/TT = 128 tiles per batch
    const int t0 = (blockIdx.x & 127) * TT;
    const int j = threadIdx.x;                   // output column 0..511
    __shared__ float xl[TT][In];

    const float4* xsrc = (const float4*)(x + ((size_t)b * Sn + t0) * In);
    float4* xdst = (float4*)&xl[0][0];
    for (int u = j; u < TT * In / 4; u += 512) xdst[u] = xsrc[u];
    __syncthreads();

    float acc[TT];
#pragma unroll
    for (int m = 0; m < TT; ++m) acc[m] = 0.f;

    for (int i = 0; i < In; i += 4) {
        const float w0 = Wxh[(size_t)(i + 0) * Hn + j];   // coalesced across j
        const float w1 = Wxh[(size_t)(i + 1) * Hn + j];
        const float w2 = Wxh[(size_t)(i + 2) * Hn + j];
        const float w3 = Wxh[(size_t)(i + 3) * Hn + j];
#pragma unroll
        for (int m = 0; m < TT; ++m) {
            const float4 xv = *(const float4*)&xl[m][i];  // LDS broadcast
            float a = acc[m];
            a = fmaf(xv.x, w0, a);
            a = fmaf(xv.y, w1, a);
            a = fmaf(xv.z, w2, a);
            a = fmaf(xv.w, w3, a);
            acc[m] = a;
        }
    }
    const float bh = bias_h[j];
#pragma unroll
    for (int m = 0; m < TT; ++m)
        xw[((size_t)b * Sn + t0 + m) * Hn + j] = acc[m] + bh;
}

// ---------------------------------------------------------------------------
// v9 scan: 256 threads/block, one block per batch, 3-tier Whh, bit-exact.
// ---------------------------------------------------------------------------
__global__ __launch_bounds__(256, 1) void rnn_scan256(const float* __restrict__ Whh,
                                                      const float* __restrict__ xw,
                                                      float* __restrict__ hlast) {
    const int b = blockIdx.x;
    const int tid = threadIdx.x;
    const int j0 = tid * 2;                   // owned columns j0, j0+1

    __shared__ float hs[2][Hn];               // double-buffered hidden state (4 KB)
    __shared__ float wl[LK][Hn];              // LDS-resident Whh rows (128 KB)

    // Tier 1: rows 0..RK-1 -> registers (float2; coalesced: lanes=consecutive j)
    float2 wr[RK];
    const float2* wsrc2 = (const float2*)Whh + tid;   // row k at k*256 float2s
#pragma unroll
    for (int k = 0; k < RK; ++k) wr[k] = wsrc2[(size_t)k * 256];

    // Tier 2: rows RK..RK+LK-1 -> LDS (cooperative float4 copy, exact fit)
    {
        const float4* src = (const float4*)(Whh + (size_t)RK * Hn);
        float4* dst = (float4*)&wl[0][0];
#pragma unroll
        for (int u = 0; u < (LK * Hn / 4) / 256; ++u)   // 32 iterations
            dst[u * 256 + tid] = src[u * 256 + tid];
    }
    hs[0][j0] = 0.f;                          // h_0 = 0
    hs[0][j0 + 1] = 0.f;
    __syncthreads();

    // Tier 3: rows RK+LK..511 streamed; this thread's column-pair base.
    const float2* ssrc = (const float2*)(Whh + (size_t)(RK + LK) * Hn) + tid;

    float2 s0[SC], s1[SC], s2[SC], s3[SC];
#define ISSUE(BUF, C)                                                         \
    {                                                                         \
        const float2* p_ = ssrc + (size_t)(C) * SC * 256;                     \
        _Pragma("unroll") for (int u_ = 0; u_ < SC; ++u_)                     \
            BUF[u_] = p_[(size_t)u_ * 256];                                   \
    }

    // prime chunks 0..3 (rotation steady across steps: NCH % 4 == 0;
    // the tail of step t issues chunks 0..3 for step t+1)
    ISSUE(s0, 0) ISSUE(s1, 1) ISSUE(s2, 2) ISSUE(s3, 3)

    float hn0 = 0.f, hn1 = 0.f;
    for (int t = 0; t < Sn; ++t) {
        const int p = t & 1;
        // xw load issued at step start; consumed at the end (latency hidden)
        const float2 xv = *(const float2*)(xw + ((size_t)b * Sn + t) * Hn + j0);
        const float4* h4 = (const float4*)&hs[p][0];
        float a0 = 0.f, a1 = 0.f;

        // ---- k = 0..RK-1 from registers (exact ascending chain) ----
#pragma unroll
        for (int q = 0; q < RK / 4; ++q) {
            const float4 hv = h4[q];          // broadcast ds_read_b128
            a0 = fmaf(hv.x, wr[4 * q + 0].x, a0); a1 = fmaf(hv.x, wr[4 * q + 0].y, a1);
            a0 = fmaf(hv.y, wr[4 * q + 1].x, a0); a1 = fmaf(hv.y, wr[4 * q + 1].y, a1);
            a0 = fmaf(hv.z, wr[4 * q + 2].x, a0); a1 = fmaf(hv.z, wr[4 * q + 2].y, a1);
            a0 = fmaf(hv.w, wr[4 * q + 3].x, a0); a1 = fmaf(hv.w, wr[4 * q + 3].y, a1);
        }
        // ---- k = RK..RK+LK-1 from LDS (float2, 2-way bank alias = free) ----
#pragma unroll
        for (int q = 0; q < LK / 4; ++q) {
            const float4 hv = h4[RK / 4 + q];
            const float2 w0 = *(const float2*)&wl[4 * q + 0][j0];
            const float2 w1 = *(const float2*)&wl[4 * q + 1][j0];
            const float2 w2 = *(const float2*)&wl[4 * q + 2][j0];
            const float2 w3 = *(const float2*)&wl[4 * q + 3][j0];
            a0 = fmaf(hv.x, w0.x, a0); a1 = fmaf(hv.x, w0.y, a1);
            a0 = fmaf(hv.y, w1.x, a0); a1 = fmaf(hv.y, w1.y, a1);
            a0 = fmaf(hv.z, w2.x, a0); a1 = fmaf(hv.z, w2.y, a1);
            a0 = fmaf(hv.w, w3.x, a0); a1 = fmaf(hv.w, w3.y, a1);
        }
        // ---- k = RK+LK..511 streamed: consume chunk C, re-issue C+4 mod NCH ----
#define SCHUNK(BUF, C)                                                        \
    {                                                                         \
        _Pragma("unroll") for (int u_ = 0; u_ < SC; u_ += 4) {                \
            const float4 hv_ = h4[(RK + LK) / 4 + ((C) * SC + u_) / 4];       \
            a0 = fmaf(hv_.x, BUF[u_ + 0].x, a0); a1 = fmaf(hv_.x, BUF[u_ + 0].y, a1); \
            a0 = fmaf(hv_.y, BUF[u_ + 1].x, a0); a1 = fmaf(hv_.y, BUF[u_ + 1].y, a1); \
            a0 = fmaf(hv_.z, BUF[u_ + 2].x, a0); a1 = fmaf(hv_.z, BUF[u_ + 2].y, a1); \
            a0 = fmaf(hv_.w, BUF[u_ + 3].x, a0); a1 = fmaf(hv_.w, BUF[u_ + 3].y, a1); \
        }                                                                     \
        ISSUE(BUF, ((C) + 4) % NCH)                                           \
    }

#pragma unroll
        for (int cc = 0; cc < NCH; cc += 4) {
            SCHUNK(s0, cc + 0)
            SCHUNK(s1, cc + 1)
            SCHUNK(s2, cc + 2)
            SCHUNK(s3, cc + 3)
        }

        hn0 = xla_tanh(xv.x + a0);            // exact association: xw + hacc
        hn1 = xla_tanh(xv.y + a1);
        hs[1 - p][j0] = hn0;
        hs[1 - p][j0 + 1] = hn1;
        __syncthreads();                      // one barrier per step
    }
    hlast[(size_t)b * Hn + j0] = hn0;
    hlast[(size_t)b * Hn + j0 + 1] = hn1;
}

// ---------------------------------------------------------------------------
// Fallback scan (v7-proven, used only if workspace can't hold xw).
// ---------------------------------------------------------------------------
#define CHUNKL(WP, HP4, CUR, NXT, C, N, A0, A1)                               \
    {                                                                         \
        if ((C) + 2 < (N)) {                                                  \
            _Pragma("unroll") for (int u_ = 0; u_ < CH; ++u_)                 \
                NXT[u_] = (WP)[(size_t)(((C) + 2) * CH + u_) * 256];          \
        }                                                                     \
        _Pragma("unroll") for (int u_ = 0; u_ < CH; u_ += 4) {                \
            const float4 hv_ = (HP4)[((C) * CH + u_) >> 2];                   \
            A0 = fmaf(hv_.x, CUR[u_ + 0].x, A0); A1 = fmaf(hv_.x, CUR[u_ + 0].y, A1); \
            A0 = fmaf(hv_.y, CUR[u_ + 1].x, A0); A1 = fmaf(hv_.y, CUR[u_ + 1].y, A1); \
            A0 = fmaf(hv_.z, CUR[u_ + 2].x, A0); A1 = fmaf(hv_.z, CUR[u_ + 2].y, A1); \
            A0 = fmaf(hv_.w, CUR[u_ + 3].x, A0); A1 = fmaf(hv_.w, CUR[u_ + 3].y, A1); \
        }                                                                     \
    }

__global__ __launch_bounds__(256, 1) void rnn_fallback(
        const float* __restrict__ Whh, const float* __restrict__ x,
        const float* __restrict__ Wxh, const float* __restrict__ bias_h,
        float* __restrict__ hlast) {
    const int b = blockIdx.x;
    const int tid = threadIdx.x;
    const int j0 = tid * 2;

    __shared__ float hs[2][Hn];
    __shared__ float xr[2][In];

    hs[0][j0] = 0.f;
    hs[0][j0 + 1] = 0.f;
    const float bh0 = bias_h[j0];
    const float bh1 = bias_h[j0 + 1];
    xr[0][tid] = x[(size_t)b * Sn * In + tid];
    __syncthreads();

    const float2* wp = (const float2*)Whh + tid;
    float2 wa[CH], wb[CH], wc[CH], wd[CH];
    float hn0 = 0.f, hn1 = 0.f;

    for (int t = 0; t < Sn; ++t) {
        const int p = t & 1;
        const float4* h4 = (const float4*)&hs[p][0];
        float a0 = 0.f, a1 = 0.f;

        float xnext = 0.f;
        if (t + 1 < Sn) xnext = x[((size_t)b * Sn + t + 1) * In + tid];

        const float2* wxp = (const float2*)Wxh + tid;
        const float4* x4 = (const float4*)&xr[p][0];
        float xa0 = 0.f, xa1 = 0.f;
#pragma unroll
        for (int u = 0; u < CH; ++u) {
            wa[u] = wxp[(size_t)u * 256];
            wb[u] = wxp[(size_t)(CH + u) * 256];
        }
        CHUNKL(wxp, x4, wa, wc, 0, 8, xa0, xa1);
        CHUNKL(wxp, x4, wb, wd, 1, 8, xa0, xa1);
        CHUNKL(wxp, x4, wc, wa, 2, 8, xa0, xa1);
        CHUNKL(wxp, x4, wd, wb, 3, 8, xa0, xa1);
        CHUNKL(wxp, x4, wa, wc, 4, 8, xa0, xa1);
        CHUNKL(wxp, x4, wb, wd, 5, 8, xa0, xa1);
        CHUNKL(wxp, x4, wc, wa, 6, 8, xa0, xa1);
        CHUNKL(wxp, x4, wd, wb, 7, 8, xa0, xa1);
        const float xw0 = xa0 + bh0;
        const float xw1 = xa1 + bh1;

#pragma unroll
        for (int u = 0; u < CH; ++u) {
            wa[u] = wp[(size_t)u * 256];
            wb[u] = wp[(size_t)(CH + u) * 256];
        }
        for (int cc = 0; cc < 16; cc += 4) {
            CHUNKL(wp, h4, wa, wc, cc + 0, 16, a0, a1);
            CHUNKL(wp, h4, wb, wd, cc + 1, 16, a0, a1);
            CHUNKL(wp, h4, wc, wa, cc + 2, 16, a0, a1);
            CHUNKL(wp, h4, wd, wb, cc + 3, 16, a0, a1);
        }
        if (t + 1 < Sn) xr[1 - p][tid] = xnext;

        const float u0 = xw0 + a0;
        const float u1 = xw1 + a1;
        hn0 = xla_tanh(u0);
        hn1 = xla_tanh(u1);
        hs[1 - p][j0] = hn0;
        hs[1 - p][j0 + 1] = hn1;
        __syncthreads();
    }
    hlast[(size_t)b * Hn + j0] = hn0;
    hlast[(size_t)b * Hn + j0 + 1] = hn1;
}

// ---------------------------------------------------------------------------
// y[b][o] = fma-chain_k(h_last[b][k]*Why[k][o]) + bias_y[o]  (unchanged, exact)
// ---------------------------------------------------------------------------
__global__ __launch_bounds__(256) void out_gemm(const float* __restrict__ hlast,
                                                const float* __restrict__ Why,
                                                const float* __restrict__ bias_y,
                                                float* __restrict__ y) {
    const int b = blockIdx.x, o = threadIdx.x;
    __shared__ float hs[Hn];
    hs[o] = hlast[(size_t)b * Hn + o];
    hs[o + 256] = hlast[(size_t)b * Hn + o + 256];
    __syncthreads();
    float acc = 0.0f;
#pragma unroll 8
    for (int k = 0; k < Hn; ++k)
        acc = fmaf(hs[k], Why[(size_t)k * On + o], acc);
    y[(size_t)b * On + o] = acc + bias_y[o];
}

// ---------------------------------------------------------------------------
extern "C" void kernel_launch(void* const* d_in, const int* in_sizes, int n_in,
                              void* d_out, int out_size, void* d_ws, size_t ws_size,
                              hipStream_t stream) {
    // Map inputs by size (x=33554432, Whh=262144, Wxh/Why=131072 in order,
    // bias_h=512, bias_y=256).
    const float *x = nullptr, *Wxh = nullptr, *Whh = nullptr, *Why = nullptr,
                *bias_h = nullptr, *bias_y = nullptr;
    for (int i = 0; i < n_in; ++i) {
        const float* p = (const float*)d_in[i];
        const int sz = in_sizes[i];
        if (sz == Bn * Sn * In) x = p;
        else if (sz == Hn * Hn) Whh = p;
        else if (sz == In * Hn) { if (!Wxh) Wxh = p; else Why = p; }
        else if (sz == Hn) bias_h = p;
        else if (sz == On) bias_y = p;
    }
    float* y = (float*)d_out;

    // workspace: hlast (128 KB) + xw (64*2048*512 f32 = 256 MB, if it fits).
    // No memset needed: both regions fully written before read.
    char* ws = (char*)d_ws;
    float* hlast = (float*)ws;
    const size_t hlast_bytes = (size_t)Bn * Hn * sizeof(float);
    float* xw = (float*)(ws + hlast_bytes);
    const size_t xw_bytes = (size_t)Bn * Sn * Hn * sizeof(float);

    if (ws_size >= hlast_bytes + xw_bytes) {
        xw_gemm<<<dim3(Bn * (Sn / TT)), dim3(512), 0, stream>>>(x, Wxh, bias_h, xw);
        rnn_scan256<<<dim3(Bn), dim3(256), 0, stream>>>(Whh, xw, hlast);
    } else {
        rnn_fallback<<<dim3(Bn), dim3(256), 0, stream>>>(Whh, x, Wxh, bias_h, hlast);
    }
    out_gemm<<<dim3(Bn), dim3(On), 0, stream>>>(hlast, Why, bias_y, y);
}

// Round 9
// 26106.088 us; speedup vs baseline: 19.0636x; 19.0636x over previous
//
#include <hip/hip_runtime.h>
#include <stdint.h>

// Problem constants (B,S,I,H,O) = (64, 2048, 256, 512, 256), all fp32.
#define Bn 64
#define Sn 2048
#define In 256
#define Hn 512
#define On 256
#define TT 16      // timesteps per xw-precompute tile
#define CH 32      // fallback-path chunk rows

// v10 scan streaming: Whh through LDS via global_load_lds DMA.
#define CHR 16              // rows per chunk
#define NCHK (Hn / CHR)     // 32 chunks/step; 32 % 4 == 0 -> ring aligns with 4 bufs
#define SEGS 32             // 1KB segments per chunk (CHR*Hn*4 / 1024)
#define SEGW 8              // segments per wave (SEGS / 4 waves)

// ---------------------------------------------------------------------------
// BIT-EXACT constraint (proven, absmax 0.0): per output element
//   xacc = fma-chain_{i=0..255 asc}(x[i], Wxh[i][j]);  xw = xacc + bias_h[j]
//   hacc = fma-chain_{k=0..511 asc}(h[k], Whh[k][j]);  u  = xw + hacc
//   h' = xla_tanh(u);   y = fma-chain_k(h[k],Why[k][o]) + bias_y[o]
//
// DESIGN v10 — evidence ledger:
//  v0 (33.7ms): cross-block rendezvous -> 16.4us/step protocol latency.
//  v2-v5 (~120ms): agent-scope polling saturates coherent fabric. Dead end.
//  v6 (328ms) & v9 (498ms): register-resident weight tiers -> allocator
//     spill catastrophes (WRITE 49.7GB / 19.2MB + FETCH 121GB scratch
//     churn; VGPR capped at 256 arch regs). REGISTER TIERING IS DEAD.
//  v7 (30.0ms, BEST): 1 block/batch, Whh streamed global->VGPR. WRITE 128B,
//     VALUBusy 3.6%. Step 14.3us = 1MB / ~70GB/s: the VGPR-return path is a
//     RATE ceiling (128KB already in flight -> not latency-bound).
//  v8 (39.8ms): 512thr tier variant, same spill story (VGPR capped 128).
// v10 = v7's structure, delivery switched to the DMA path:
//   * global_load_lds (L2 -> LDS direct, 16B/lane, 1KB/wave-instr): m97 GEMM
//     sustained ~200GB/s/CU through this path with the same chunked-barrier
//     structure — ~3x the VGPR-return rate.
//   * 4 x 32KB LDS ring, 16-row chunks, prefetch distance 3, counted
//     s_waitcnt vmcnt(16) + raw s_barrier per chunk (T3/T4: never drain
//     in the loop). Ring continues across steps (chunk%4 == buffer).
//   * consume: ds_read_b64 of the thread's 2 cols (LDS 128B/cy -> 3.4us/step
//     floor); h from LDS double-buffer via b128 broadcasts.
//   * xw loaded at step START (oldest in vmcnt queue -> counted waits stay
//     sound; compiler's own wait for its use is counted, not a drain).
//   * regs ~60 VGPR: NO spill exposure. LDS 135168B (v9-launch-proven size).
//   * s_waitcnt vmcnt(0) after the t-loop: no DMA lands after LDS dealloc.
// ---------------------------------------------------------------------------

typedef const __attribute__((address_space(1))) void GAS;
typedef __attribute__((address_space(3))) void LAS;

__device__ __forceinline__ float xla_tanh(float x) {
    const float ax = __builtin_fabsf(x);
    float xc = fmaxf(-7.99881172180175781f, fminf(7.99881172180175781f, x));
    const float x2 = xc * xc;
    float p = fmaf(x2, -2.76076847742355e-16f, 2.00018790482477e-13f);
    p = fmaf(x2, p, -8.60467152213735e-11f);
    p = fmaf(x2, p, 5.12229709037114e-08f);
    p = fmaf(x2, p, 1.48572235717979e-05f);
    p = fmaf(x2, p, 6.37261928875436e-04f);
    p = fmaf(x2, p, 4.89352455891786e-03f);
    p = xc * p;
    float q = fmaf(x2, 1.19825839466702e-06f, 1.18534705686654e-04f);
    q = fmaf(x2, q, 2.26843463243900e-03f);
    q = fmaf(x2, q, 4.89352518554385e-03f);
    return ax < 0.0004f ? x : p / q;
}

// ---------------------------------------------------------------------------
// xw[b][t][j] = bias_h[j] + fma-chain_{i asc}(x[b][t][i], Wxh[i][j])
// (proven bit-exact in v7)
// ---------------------------------------------------------------------------
__global__ __launch_bounds__(512) void xw_gemm(const float* __restrict__ x,
                                               const float* __restrict__ Wxh,
                                               const float* __restrict__ bias_h,
                                               float* __restrict__ xw) {
    const int b = blockIdx.x >> 7;               // Sn/TT = 128 tiles per batch
    const int t0 = (blockIdx.x & 127) * TT;
    const int j = threadIdx.x;                   // output column 0..511
    __shared__ float xl[TT][In];

    const float4* xsrc = (const float4*)(x + ((size_t)b * Sn + t0) * In);
    float4* xdst = (float4*)&xl[0][0];
    for (int u = j; u < TT * In / 4; u += 512) xdst[u] = xsrc[u];
    __syncthreads();

    float acc[TT];
#pragma unroll
    for (int m = 0; m < TT; ++m) acc[m] = 0.f;

    for (int i = 0; i < In; i += 4) {
        const float w0 = Wxh[(size_t)(i + 0) * Hn + j];   // coalesced across j
        const float w1 = Wxh[(size_t)(i + 1) * Hn + j];
        const float w2 = Wxh[(size_t)(i + 2) * Hn + j];
        const float w3 = Wxh[(size_t)(i + 3) * Hn + j];
#pragma unroll
        for (int m = 0; m < TT; ++m) {
            const float4 xv = *(const float4*)&xl[m][i];  // LDS broadcast
            float a = acc[m];
            a = fmaf(xv.x, w0, a);
            a = fmaf(xv.y, w1, a);
            a = fmaf(xv.z, w2, a);
            a = fmaf(xv.w, w3, a);
            acc[m] = a;
        }
    }
    const float bh = bias_h[j];
#pragma unroll
    for (int m = 0; m < TT; ++m)
        xw[((size_t)b * Sn + t0 + m) * Hn + j] = acc[m] + bh;
}

// ---------------------------------------------------------------------------
// v10 scan: 256 threads/block, 1 block/batch; Whh DMA-streamed through an
// LDS ring; counted-vmcnt pipeline; bit-exact chains.
// ---------------------------------------------------------------------------

// Fill chunk NC (16 rows) into ring buffer NB: this wave's 8 x 1KB segments.
// Global src is per-lane (base + lane*16B); LDS dest is wave-uniform.
#define FILLC(NC, NB)                                                         \
    {                                                                         \
        const float* gb_ = Whh + (size_t)(NC) * (CHR * Hn);                   \
        float* lb_ = &wbuf[(NB)][0];                                          \
        _Pragma("unroll") for (int si_ = 0; si_ < SEGW; ++si_) {              \
            const int seg_ = wv * SEGW + si_;                                 \
            __builtin_amdgcn_global_load_lds(                                 \
                (GAS*)(gb_ + seg_ * 256 + lane * 4),                          \
                (LAS*)(lb_ + seg_ * 256), 16, 0, 0);                          \
        }                                                                     \
    }

// One pipeline stage: wait own fills for chunk C landed (all but the newest
// 16 retired = iters C-1,C-2's fills), barrier (everyone's landed AND all
// waves consumed chunk C-1 -> safe to overwrite its buffer), issue fill for
// chunk (C+3)&31 into buffer (BI+3)&3, consume chunk C from buffer BI.
#define ITER(C, BI)                                                           \
    {                                                                         \
        asm volatile("s_waitcnt vmcnt(16)" ::: "memory");                     \
        __builtin_amdgcn_s_barrier();                                         \
        FILLC(((C) + 3) & 31, ((BI) + 3) & 3)                                 \
        const int kb_ = (C) * CHR;                                            \
        const float* wrow_ = &wbuf[(BI)][0];                                  \
        _Pragma("unroll") for (int q_ = 0; q_ < CHR / 4; ++q_) {              \
            const float4 hv_ = h4[(kb_ >> 2) + q_];                           \
            const float2 w0_ = *(const float2*)(wrow_ + (4 * q_ + 0) * Hn + j0); \
            const float2 w1_ = *(const float2*)(wrow_ + (4 * q_ + 1) * Hn + j0); \
            const float2 w2_ = *(const float2*)(wrow_ + (4 * q_ + 2) * Hn + j0); \
            const float2 w3_ = *(const float2*)(wrow_ + (4 * q_ + 3) * Hn + j0); \
            a0 = fmaf(hv_.x, w0_.x, a0); a1 = fmaf(hv_.x, w0_.y, a1);         \
            a0 = fmaf(hv_.y, w1_.x, a0); a1 = fmaf(hv_.y, w1_.y, a1);         \
            a0 = fmaf(hv_.z, w2_.x, a0); a1 = fmaf(hv_.z, w2_.y, a1);         \
            a0 = fmaf(hv_.w, w3_.x, a0); a1 = fmaf(hv_.w, w3_.y, a1);         \
        }                                                                     \
    }

__global__ __launch_bounds__(256, 1) void rnn_dma(const float* __restrict__ Whh,
                                                  const float* __restrict__ xw,
                                                  float* __restrict__ hlast) {
    const int b = blockIdx.x;
    const int tid = threadIdx.x;
    const int j0 = tid * 2;                   // owned columns j0, j0+1
    const int wv = tid >> 6;                  // wave 0..3
    const int lane = tid & 63;

    __shared__ float wbuf[4][CHR * Hn];       // 4 x 32KB DMA ring = 128KB
    __shared__ float hs[2][Hn];               // double-buffered hidden (4KB)

    hs[0][j0] = 0.f;                          // h_0 = 0
    hs[0][j0 + 1] = 0.f;
    __syncthreads();

    // Prime the ring: chunks 0,1,2 -> buffers 0,1,2.
    FILLC(0, 0) FILLC(1, 1) FILLC(2, 2)

    float hn0 = 0.f, hn1 = 0.f;
    for (int t = 0; t < Sn; ++t) {
        const int p = t & 1;
        // xw issued at step START: oldest in the vmcnt queue, so the counted
        // per-iter waits retire it for free and its use-wait is counted.
        const float2 xv = *(const float2*)(xw + ((size_t)b * Sn + t) * Hn + j0);
        const float4* h4 = (const float4*)&hs[p][0];
        float a0 = 0.f, a1 = 0.f;

        // 32 chunks, k ascending 0..511; ring fills cover the NEXT step's
        // chunks automatically (chunk%4 == buffer, 32%4 == 0).
        for (int cb = 0; cb < NCHK; cb += 4) {
            ITER(cb + 0, 0)
            ITER(cb + 1, 1)
            ITER(cb + 2, 2)
            ITER(cb + 3, 3)
        }

        hn0 = xla_tanh(xv.x + a0);            // exact association: xw + hacc
        hn1 = xla_tanh(xv.y + a1);
        hs[1 - p][j0] = hn0;
        hs[1 - p][j0 + 1] = hn1;
        // step-boundary: publish h via LDS; raw barrier + lgkm drain only
        // (vmcnt NOT drained -> ring fills stay in flight across steps)
        asm volatile("s_waitcnt lgkmcnt(0)" ::: "memory");
        __builtin_amdgcn_s_barrier();
    }

    // Drain outstanding ring DMA before any wave can end (LDS dealloc safety).
    asm volatile("s_waitcnt vmcnt(0)" ::: "memory");
    hlast[(size_t)b * Hn + j0] = hn0;
    hlast[(size_t)b * Hn + j0 + 1] = hn1;
}

// ---------------------------------------------------------------------------
// Fallback scan (v7-proven, used only if workspace can't hold xw).
// ---------------------------------------------------------------------------
#define CHUNKL(WP, HP4, CUR, NXT, C, N, A0, A1)                               \
    {                                                                         \
        if ((C) + 2 < (N)) {                                                  \
            _Pragma("unroll") for (int u_ = 0; u_ < CH; ++u_)                 \
                NXT[u_] = (WP)[(size_t)(((C) + 2) * CH + u_) * 256];          \
        }                                                                     \
        _Pragma("unroll") for (int u_ = 0; u_ < CH; u_ += 4) {                \
            const float4 hv_ = (HP4)[((C) * CH + u_) >> 2];                   \
            A0 = fmaf(hv_.x, CUR[u_ + 0].x, A0); A1 = fmaf(hv_.x, CUR[u_ + 0].y, A1); \
            A0 = fmaf(hv_.y, CUR[u_ + 1].x, A0); A1 = fmaf(hv_.y, CUR[u_ + 1].y, A1); \
            A0 = fmaf(hv_.z, CUR[u_ + 2].x, A0); A1 = fmaf(hv_.z, CUR[u_ + 2].y, A1); \
            A0 = fmaf(hv_.w, CUR[u_ + 3].x, A0); A1 = fmaf(hv_.w, CUR[u_ + 3].y, A1); \
        }                                                                     \
    }

__global__ __launch_bounds__(256, 1) void rnn_fallback(
        const float* __restrict__ Whh, const float* __restrict__ x,
        const float* __restrict__ Wxh, const float* __restrict__ bias_h,
        float* __restrict__ hlast) {
    const int b = blockIdx.x;
    const int tid = threadIdx.x;
    const int j0 = tid * 2;

    __shared__ float hs[2][Hn];
    __shared__ float xr[2][In];

    hs[0][j0] = 0.f;
    hs[0][j0 + 1] = 0.f;
    const float bh0 = bias_h[j0];
    const float bh1 = bias_h[j0 + 1];
    xr[0][tid] = x[(size_t)b * Sn * In + tid];
    __syncthreads();

    const float2* wp = (const float2*)Whh + tid;
    float2 wa[CH], wb[CH], wc[CH], wd[CH];
    float hn0 = 0.f, hn1 = 0.f;

    for (int t = 0; t < Sn; ++t) {
        const int p = t & 1;
        const float4* h4 = (const float4*)&hs[p][0];
        float a0 = 0.f, a1 = 0.f;

        float xnext = 0.f;
        if (t + 1 < Sn) xnext = x[((size_t)b * Sn + t + 1) * In + tid];

        const float2* wxp = (const float2*)Wxh + tid;
        const float4* x4 = (const float4*)&xr[p][0];
        float xa0 = 0.f, xa1 = 0.f;
#pragma unroll
        for (int u = 0; u < CH; ++u) {
            wa[u] = wxp[(size_t)u * 256];
            wb[u] = wxp[(size_t)(CH + u) * 256];
        }
        CHUNKL(wxp, x4, wa, wc, 0, 8, xa0, xa1);
        CHUNKL(wxp, x4, wb, wd, 1, 8, xa0, xa1);
        CHUNKL(wxp, x4, wc, wa, 2, 8, xa0, xa1);
        CHUNKL(wxp, x4, wd, wb, 3, 8, xa0, xa1);
        CHUNKL(wxp, x4, wa, wc, 4, 8, xa0, xa1);
        CHUNKL(wxp, x4, wb, wd, 5, 8, xa0, xa1);
        CHUNKL(wxp, x4, wc, wa, 6, 8, xa0, xa1);
        CHUNKL(wxp, x4, wd, wb, 7, 8, xa0, xa1);
        const float xw0 = xa0 + bh0;
        const float xw1 = xa1 + bh1;

#pragma unroll
        for (int u = 0; u < CH; ++u) {
            wa[u] = wp[(size_t)u * 256];
            wb[u] = wp[(size_t)(CH + u) * 256];
        }
        for (int cc = 0; cc < 16; cc += 4) {
            CHUNKL(wp, h4, wa, wc, cc + 0, 16, a0, a1);
            CHUNKL(wp, h4, wb, wd, cc + 1, 16, a0, a1);
            CHUNKL(wp, h4, wc, wa, cc + 2, 16, a0, a1);
            CHUNKL(wp, h4, wd, wb, cc + 3, 16, a0, a1);
        }
        if (t + 1 < Sn) xr[1 - p][tid] = xnext;

        const float u0 = xw0 + a0;
        const float u1 = xw1 + a1;
        hn0 = xla_tanh(u0);
        hn1 = xla_tanh(u1);
        hs[1 - p][j0] = hn0;
        hs[1 - p][j0 + 1] = hn1;
        __syncthreads();
    }
    hlast[(size_t)b * Hn + j0] = hn0;
    hlast[(size_t)b * Hn + j0 + 1] = hn1;
}

// ---------------------------------------------------------------------------
// y[b][o] = fma-chain_k(h_last[b][k]*Why[k][o]) + bias_y[o]  (unchanged, exact)
// ---------------------------------------------------------------------------
__global__ __launch_bounds__(256) void out_gemm(const float* __restrict__ hlast,
                                                const float* __restrict__ Why,
                                                const float* __restrict__ bias_y,
                                                float* __restrict__ y) {
    const int b = blockIdx.x, o = threadIdx.x;
    __shared__ float hs[Hn];
    hs[o] = hlast[(size_t)b * Hn + o];
    hs[o + 256] = hlast[(size_t)b * Hn + o + 256];
    __syncthreads();
    float acc = 0.0f;
#pragma unroll 8
    for (int k = 0; k < Hn; ++k)
        acc = fmaf(hs[k], Why[(size_t)k * On + o], acc);
    y[(size_t)b * On + o] = acc + bias_y[o];
}

// ---------------------------------------------------------------------------
extern "C" void kernel_launch(void* const* d_in, const int* in_sizes, int n_in,
                              void* d_out, int out_size, void* d_ws, size_t ws_size,
                              hipStream_t stream) {
    // Map inputs by size (x=33554432, Whh=262144, Wxh/Why=131072 in order,
    // bias_h=512, bias_y=256).
    const float *x = nullptr, *Wxh = nullptr, *Whh = nullptr, *Why = nullptr,
                *bias_h = nullptr, *bias_y = nullptr;
    for (int i = 0; i < n_in; ++i) {
        const float* p = (const float*)d_in[i];
        const int sz = in_sizes[i];
        if (sz == Bn * Sn * In) x = p;
        else if (sz == Hn * Hn) Whh = p;
        else if (sz == In * Hn) { if (!Wxh) Wxh = p; else Why = p; }
        else if (sz == Hn) bias_h = p;
        else if (sz == On) bias_y = p;
    }
    float* y = (float*)d_out;

    // workspace: hlast (128 KB) + xw (64*2048*512 f32 = 256 MB, if it fits).
    // No memset needed: both regions fully written before read.
    char* ws = (char*)d_ws;
    float* hlast = (float*)ws;
    const size_t hlast_bytes = (size_t)Bn * Hn * sizeof(float);
    float* xw = (float*)(ws + hlast_bytes);
    const size_t xw_bytes = (size_t)Bn * Sn * Hn * sizeof(float);

    if (ws_size >= hlast_bytes + xw_bytes) {
        xw_gemm<<<dim3(Bn * (Sn / TT)), dim3(512), 0, stream>>>(x, Wxh, bias_h, xw);
        rnn_dma<<<dim3(Bn), dim3(256), 0, stream>>>(Whh, xw, hlast);
    } else {
        rnn_fallback<<<dim3(Bn), dim3(256), 0, stream>>>(Whh, x, Wxh, bias_h, hlast);
    }
    out_gemm<<<dim3(Bn), dim3(On), 0, stream>>>(hlast, Why, bias_y, y);
}